// Round 2
// 585.730 us; speedup vs baseline: 1.0014x; 1.0014x over previous
//
#include <hip/hip_runtime.h>

// QLSTM: B=512, T=1024, IN=1, H=64.
// 4 waves per batch element (block=256), one gate per wave:
//   wave 0 -> i, wave 1 -> f, wave 2 -> g, wave 3 -> o   (PyTorch order)
// Lane l owns hidden unit l. Each wave holds its 64-wide gate row in VGPRs.
//
// R1: VGPR_Count=44 showed the compiler sank the 16 float4 weight loads into
// the t-loop (legal: W_hh is const restrict -> rematerializable).
// R2 fix: pin SCALAR floats (single-VGPR tied asm operands -- float4 "+v"
// is an unsupported indirect/multi-reg tie on gfx950). One asm per scalar,
// all outside the loop, makes the 64 weight values opaque so they must stay
// resident in VGPRs across all 1024 iterations.
//
// Sync structure (1 barrier/step):
//  - each wave keeps a PRIVATE LDS copy hs4[w][64] of the h vector; write then
//    read is same-wave DS ordering -> no barrier needed for the h broadcast.
//  - the c,h update is computed redundantly by all 4 waves; the only
//    cross-wave traffic is the 4 gate activations, exchanged through a
//    DOUBLE-BUFFERED act array (parity t&1) -> no WAR barrier.

#define TLEN 1024
#define HID  64

__device__ __forceinline__ float fast_sigmoid(float x) {
    return __builtin_amdgcn_rcpf(1.0f + __expf(-x));   // hw exp + hw rcp
}
__device__ __forceinline__ float fast_tanh(float x) {
    return __builtin_fmaf(2.0f, fast_sigmoid(2.0f * x), -1.0f);
}

__global__ __launch_bounds__(256, 2)
void qlstm_kernel(const float* __restrict__ x,      // [B, T, 1]
                  const float* __restrict__ W_ih,   // [256, 1]
                  const float* __restrict__ W_hh,   // [256, 64]
                  const float* __restrict__ b_ih,   // [256]
                  const float* __restrict__ b_hh,   // [256]
                  const float* __restrict__ W_lin,  // [1, 64]
                  const float* __restrict__ b_lin,  // [1]
                  float* __restrict__ out)          // [B]
{
    const int b   = blockIdx.x;
    const int tid = threadIdx.x;
    const int w   = tid >> 6;   // wave id == gate id
    const int l   = tid & 63;   // hidden unit

    __shared__ __align__(16) float xs[TLEN];          // 4 KB
    __shared__ __align__(16) float hs4[4][HID];       // per-wave private h
    __shared__ __align__(16) float act[2][4][HID];    // double-buffered gates

    // Stage this batch element's x row: 1024 floats, one float4 per thread.
    ((float4*)xs)[tid] = ((const float4*)(x + (size_t)b * TLEN))[tid];

    // This wave's gate row (64 weights): coalesced float4 loads, scattered
    // into 64 scalars (SROA promotes wv[] to registers: all indices static).
    const int row = w * HID + l;
    const float4* Wr = (const float4*)(W_hh + (size_t)row * HID);
    float wv[64];
    #pragma unroll
    for (int q = 0; q < 16; ++q) {
        const float4 t = Wr[q];
        wv[4 * q + 0] = t.x;
        wv[4 * q + 1] = t.y;
        wv[4 * q + 2] = t.z;
        wv[4 * q + 3] = t.w;
    }

    const float u    = W_ih[row];                 // IN == 1
    const float bias = b_ih[row] + b_hh[row];
    const float wlin = W_lin[l];

    // Pin each weight scalar in a VGPR: "+v" on a single float is a direct
    // (single-register) tie, which the backend supports. The asm output is a
    // new opaque value -> the loads cannot be sunk/rematerialized in the loop.
    #pragma unroll
    for (int k = 0; k < 64; ++k)
        asm volatile("" : "+v"(wv[k]));

    float c = 0.0f, h = 0.0f;
    hs4[w][l] = 0.0f;
    __syncthreads();   // xs + hs4 ready

    const float* hsw = hs4[w];

    for (int t = 0; t < TLEN; ++t) {
        const int p = t & 1;
        const float xt = xs[t];                   // same-address broadcast

        // acc = W_hh[row,:] . h  + x_t*u + bias   (h from private LDS copy)
        // EXACT same serial FMA order as the verified kernel (absmax 0.0).
        float acc = __builtin_fmaf(xt, u, bias);
        #pragma unroll
        for (int q = 0; q < 16; ++q) {
            const float4 hk = *(const float4*)&hsw[4 * q];  // ds_read_b128 bcast
            acc = __builtin_fmaf(hk.x, wv[4 * q + 0], acc);
            acc = __builtin_fmaf(hk.y, wv[4 * q + 1], acc);
            acc = __builtin_fmaf(hk.z, wv[4 * q + 2], acc);
            acc = __builtin_fmaf(hk.w, wv[4 * q + 3], acc);
        }

        // This wave's activation (wave-uniform branch).
        const float a = (w == 2) ? fast_tanh(acc) : fast_sigmoid(acc);
        act[p][w][l] = a;                         // stride-1, conflict-free
        __syncthreads();                          // the ONE barrier per step

        // Redundant elementwise update in every wave.
        const float ai = act[p][0][l];
        const float af = act[p][1][l];
        const float ag = act[p][2][l];
        const float ao = act[p][3][l];
        c = __builtin_fmaf(af, c, ai * ag);
        h = ao * fast_tanh(c);
        hs4[w][l] = h;                            // private copy; no barrier
    }

    // out[b] = dot(h, W_lin) + b_lin  (wave 0 only)
    if (w == 0) {
        float v = h * wlin;
        #pragma unroll
        for (int off = 32; off > 0; off >>= 1)
            v += __shfl_down(v, off, 64);
        if (l == 0) out[b] = v + b_lin[0];
    }
}

extern "C" void kernel_launch(void* const* d_in, const int* in_sizes, int n_in,
                              void* d_out, int out_size, void* d_ws, size_t ws_size,
                              hipStream_t stream) {
    const float* x     = (const float*)d_in[0];
    const float* W_ih  = (const float*)d_in[1];
    const float* W_hh  = (const float*)d_in[2];
    const float* b_ih  = (const float*)d_in[3];
    const float* b_hh  = (const float*)d_in[4];
    const float* W_lin = (const float*)d_in[5];
    const float* b_lin = (const float*)d_in[6];
    float* out = (float*)d_out;

    const int B = out_size;  // 512
    qlstm_kernel<<<B, 256, 0, stream>>>(x, W_ih, W_hh, b_ih, b_hh, W_lin, b_lin, out);
}